// Round 9
// baseline (1262.034 us; speedup 1.0000x reference)
//
#include <hip/hip_runtime.h>
#include <hip/hip_bf16.h>

#define NB 8
#define LSEQ 2048
#define HH 8
#define DD 32
#define EE 256
#define NE 32

// zinv geometry (unchanged, round-8 proven)
#define ZQT 64
#define ZNT 512
#define ZKW 256
#define ZNTILE 16

// mean+topk geometry
#define MQT 64     // queries per block
#define MKQ 512    // keys per quarter
#define MNT 512
#define MSMS 514   // smean row stride (words); 514%32==2 -> 2-way RMW (free)

typedef __attribute__((ext_vector_type(8))) short short8;
typedef __attribute__((ext_vector_type(4))) float f32x4;

// ---------------------------------------------------------------------------
// K1: per-head projection -> 3-way bf16 split (hi/mid/lo ~ 24 mantissa bits).
// Q pass folds softmax temperature AND 1/ln2: scale = 1/(16*ln2) -> exp2.
// ---------------------------------------------------------------------------
__global__ __launch_bounds__(256) void proj_kernel(const float* __restrict__ x,
                                                   const float* __restrict__ W,
                                                   float scale,
                                                   __hip_bfloat16* __restrict__ o1,
                                                   __hip_bfloat16* __restrict__ o2,
                                                   __hip_bfloat16* __restrict__ o3) {
  const int b = blockIdx.x;  // n*L + l
  __shared__ float xs[EE];
  __shared__ float Ws[DD][DD + 1];
  const int t = threadIdx.x;
  xs[t] = x[(size_t)b * EE + t];
  for (int i = t; i < DD * DD; i += 256) Ws[i / DD][i % DD] = W[i];
  __syncthreads();
  const int h = t / DD, e = t % DD;
  float acc = 0.f;
#pragma unroll
  for (int d = 0; d < DD; ++d) acc = fmaf(xs[h * DD + d], Ws[e][d], acc);
  acc *= scale;
  const int n = b / LSEQ, l = b % LSEQ;
  const size_t oi = (((size_t)n * HH + h) * LSEQ + l) * DD + e;
  __hip_bfloat16 p1 = __float2bfloat16(acc);
  float r1 = acc - __bfloat162float(p1);
  __hip_bfloat16 p2 = __float2bfloat16(r1);
  float r2 = r1 - __bfloat162float(p2);
  __hip_bfloat16 p3 = __float2bfloat16(r2);
  o1[oi] = p1;
  o2[oi] = p2;
  o3[oi] = p3;
}

// ---------------------------------------------------------------------------
// K2: Z -> inv = rcp(Z) (round-8 proven, unchanged).
// ---------------------------------------------------------------------------
__global__ __launch_bounds__(ZNT) void zinv_kernel(
    const __hip_bfloat16* __restrict__ q1, const __hip_bfloat16* __restrict__ q2,
    const __hip_bfloat16* __restrict__ q3, const __hip_bfloat16* __restrict__ k1,
    const __hip_bfloat16* __restrict__ k2, const __hip_bfloat16* __restrict__ k3,
    float* __restrict__ invp) {
  __shared__ float zlds[HH][ZQT];

  const int t = threadIdx.x;
  const int w = t >> 6, l = t & 63;
  const int g = l >> 4, c = l & 15;
  const int n = blockIdx.x & 7;
  const int q0 = (blockIdx.x >> 3) * ZQT;

  ((float*)zlds)[t] = 0.f;
  __syncthreads();

  for (int h = 0; h < HH; ++h) {
    const size_t hb = ((size_t)n * HH + h) * LSEQ;
    short8 aH[4], aM[4], aL[4];
#pragma unroll
    for (int qs = 0; qs < 4; ++qs) {
      const size_t qoff = (hb + q0 + qs * 16 + c) * DD + (size_t)g * 8;
      aH[qs] = *(const short8*)(q1 + qoff);
      aM[qs] = *(const short8*)(q2 + qoff);
      aL[qs] = *(const short8*)(q3 + qoff);
    }
    float Zl[4][4];
#pragma unroll
    for (int qs = 0; qs < 4; ++qs)
#pragma unroll
      for (int r = 0; r < 4; ++r) Zl[qs][r] = 0.f;

    for (int t2 = 0; t2 < ZNTILE; ++t2) {
      const size_t koff = (hb + (size_t)w * ZKW + t2 * 16 + c) * DD + (size_t)g * 8;
      const short8 bH = *(const short8*)(k1 + koff);
      const short8 bM = *(const short8*)(k2 + koff);
      const short8 bL = *(const short8*)(k3 + koff);
#pragma unroll
      for (int qs = 0; qs < 4; ++qs) {
        f32x4 a = {0.f, 0.f, 0.f, 0.f};
        a = __builtin_amdgcn_mfma_f32_16x16x32_bf16(aH[qs], bH, a, 0, 0, 0);
        a = __builtin_amdgcn_mfma_f32_16x16x32_bf16(aH[qs], bM, a, 0, 0, 0);
        a = __builtin_amdgcn_mfma_f32_16x16x32_bf16(aM[qs], bH, a, 0, 0, 0);
        a = __builtin_amdgcn_mfma_f32_16x16x32_bf16(aH[qs], bL, a, 0, 0, 0);
        a = __builtin_amdgcn_mfma_f32_16x16x32_bf16(aL[qs], bH, a, 0, 0, 0);
        a = __builtin_amdgcn_mfma_f32_16x16x32_bf16(aM[qs], bM, a, 0, 0, 0);
#pragma unroll
        for (int r = 0; r < 4; ++r) Zl[qs][r] += exp2f(a[r]);
      }
    }
#pragma unroll
    for (int msk = 1; msk <= 8; msk <<= 1)
#pragma unroll
      for (int qs = 0; qs < 4; ++qs)
#pragma unroll
        for (int r = 0; r < 4; ++r) Zl[qs][r] += __shfl_xor(Zl[qs][r], msk);
    if (c == 0) {
#pragma unroll
      for (int qs = 0; qs < 4; ++qs)
#pragma unroll
        for (int r = 0; r < 4; ++r) atomicAdd(&zlds[h][qs * 16 + g * 4 + r], Zl[qs][r]);
    }
  }
  __syncthreads();
  const int h2 = t >> 6, qi = t & 63;
  invp[((size_t)n * HH + h2) * LSEQ + q0 + qi] = __builtin_amdgcn_rcpf(zlds[h2][qi]);
}

// ---------------------------------------------------------------------------
// K3: quarter-K mean + per-quarter top-32 candidates.
// Block = (n, 64q tile, k-quarter of 512). 8 waves = 4 q-subtiles x 2 k-subtiles:
// the 4 q-waves read the SAME K lines -> x4 L1 reuse (pacing barrier each 4 t2
// keeps the active K window ~24KB < 32KB L1). Mean slice lives in LDS (131KB,
// 2-way-free RMW). Then proven topk per row on the 512 slice -> 32 candidates.
// C fragment mapping (verified rounds 2-8): row(query)=g*4+r, col(key)=c.
// ---------------------------------------------------------------------------
__global__ __launch_bounds__(MNT) void mean_topk_kernel(
    const __hip_bfloat16* __restrict__ q1, const __hip_bfloat16* __restrict__ q2,
    const __hip_bfloat16* __restrict__ q3, const __hip_bfloat16* __restrict__ k1,
    const __hip_bfloat16* __restrict__ k2, const __hip_bfloat16* __restrict__ k3,
    const float* __restrict__ invp, float* __restrict__ candV,
    int* __restrict__ candI) {
  __shared__ float smean[MQT * MSMS];  // 131.6 KB
  __shared__ float ilds[HH][MQT];      // 2 KB

  const int t = threadIdx.x;
  const int w = t >> 6, l = t & 63;
  const int g = l >> 4, c = l & 15;
  const int qs = w >> 1, ks = w & 1;
  const int n = blockIdx.x & 7;        // 1024 blocks, %8==0: bijective XCD map
  const int rest = blockIdx.x >> 3;    // 0..127
  const int qt = rest & 31;
  const int kq = rest >> 5;            // 0..3
  const int q0 = qt * MQT;
  const int k0 = kq * MKQ;

  for (int i = t; i < MQT * MSMS; i += MNT) smean[i] = 0.f;
  for (int i = t; i < HH * MQT; i += MNT) {
    const int h = i >> 6, qi = i & 63;
    ilds[h][qi] = invp[((size_t)n * HH + h) * LSEQ + q0 + qi];
  }
  float* macc = &smean[(qs * 16 + g * 4) * MSMS + ks * 256 + c];
  __syncthreads();

  for (int h = 0; h < HH; ++h) {
    const size_t hb = ((size_t)n * HH + h) * LSEQ;
    const size_t qoff = (hb + q0 + qs * 16 + c) * DD + (size_t)g * 8;
    const short8 aH = *(const short8*)(q1 + qoff);
    const short8 aM = *(const short8*)(q2 + qoff);
    const short8 aL = *(const short8*)(q3 + qoff);
    float iv[4];
#pragma unroll
    for (int r = 0; r < 4; ++r) iv[r] = ilds[h][qs * 16 + g * 4 + r];

    for (int sub = 0; sub < 4; ++sub) {
#pragma unroll
      for (int t2i = 0; t2i < 4; ++t2i) {
        const int t2 = sub * 4 + t2i;
        const size_t koff =
            (hb + k0 + ks * 256 + t2 * 16 + c) * DD + (size_t)g * 8;
        const short8 bH = *(const short8*)(k1 + koff);
        const short8 bM = *(const short8*)(k2 + koff);
        const short8 bL = *(const short8*)(k3 + koff);
        f32x4 a = {0.f, 0.f, 0.f, 0.f};
        a = __builtin_amdgcn_mfma_f32_16x16x32_bf16(aH, bH, a, 0, 0, 0);
        a = __builtin_amdgcn_mfma_f32_16x16x32_bf16(aH, bM, a, 0, 0, 0);
        a = __builtin_amdgcn_mfma_f32_16x16x32_bf16(aM, bH, a, 0, 0, 0);
        a = __builtin_amdgcn_mfma_f32_16x16x32_bf16(aH, bL, a, 0, 0, 0);
        a = __builtin_amdgcn_mfma_f32_16x16x32_bf16(aL, bH, a, 0, 0, 0);
        a = __builtin_amdgcn_mfma_f32_16x16x32_bf16(aM, bM, a, 0, 0, 0);
#pragma unroll
        for (int r = 0; r < 4; ++r) {
          float* p = macc + r * MSMS + t2 * 16;
          *p = fmaf(exp2f(a[r]), iv[r], *p);
        }
      }
      __syncthreads();  // pacing: keep q-waves on the same K window (L1 reuse)
    }
  }

  // --- per-row top-32 of this 512 slice (proven topk, j<8); wave w: rows w*8.. ---
#pragma unroll 1
  for (int rr = 0; rr < 8; ++rr) {
    const int row = w * 8 + rr;
    float* rowp = &smean[row * MSMS];
    float vals[8];
    float v1 = -1e30f, v2 = -1e30f;
    int i1 = 1 << 30, i2 = 1 << 30;
#pragma unroll
    for (int j = 0; j < 8; ++j) {
      float v = rowp[j * 64 + l];
      vals[j] = v;
      const int k = j * 64 + l;
      if (v > v1) { v2 = v1; i2 = i1; v1 = v; i1 = k; }
      else if (v > v2) { v2 = v; i2 = k; }
    }
    unsigned rem = 0u;
    int selk = 0;
    float selv = 0.f;
#pragma unroll 1
    for (int it = 0; it < NE; ++it) {
      float bv = v1;
      int bk = i1;
#pragma unroll
      for (int off = 32; off >= 1; off >>= 1) {
        float ov = __shfl_xor(bv, off);
        int ok = __shfl_xor(bk, off);
        if (ov > bv || (ov == bv && ok < bk)) { bv = ov; bk = ok; }
      }
      if (l == it) { selk = bk; selv = bv; }
      if (i1 == bk) {  // unique owner (k%64==l)
        rem |= 1u << (bk >> 6);
        if (i2 != (1 << 30)) {
          v1 = v2; i1 = i2;
          v2 = -1e30f; i2 = 1 << 30;
        } else {
          v1 = -1e30f; i1 = 1 << 30;
          v2 = -1e30f; i2 = 1 << 30;
#pragma unroll
          for (int j = 0; j < 8; ++j) {
            float v = ((rem >> j) & 1u) ? -1e30f : vals[j];
            const int k = j * 64 + l;
            if (v > v1) { v2 = v1; i2 = i1; v1 = v; i1 = k; }
            else if (v > v2) { v2 = v; i2 = k; }
          }
        }
      }
    }
    if (l < NE) {
      const size_t cb = (((size_t)n * LSEQ + q0 + row) * 4 + kq) * NE;
      candV[cb + l] = selv;
      candI[cb + l] = k0 + selk;  // global key index
    }
  }
}

// ---------------------------------------------------------------------------
// K4: merge 4x32 quarter candidates per row -> final top-32 -> sorted edges.
// Block = 512 thr = 8 waves = 8 rows. Same (val desc, idx asc) semantics.
// ---------------------------------------------------------------------------
__global__ __launch_bounds__(512) void merge_kernel(const float* __restrict__ candV,
                                                    const int* __restrict__ candI,
                                                    int* __restrict__ out) {
  const int t = threadIdx.x;
  const int w = t >> 6, l = t & 63;
  const size_t rowg = (size_t)blockIdx.x * 8 + w;  // n*2048 + q
  const int n = (int)(rowg >> 11), q = (int)(rowg & 2047);
  const size_t cb = rowg * 128;

  float v0 = candV[cb + l], v1 = candV[cb + 64 + l];
  int i0 = candI[cb + l], i1 = candI[cb + 64 + l];

  int selk = 0;
#pragma unroll 1
  for (int it = 0; it < NE; ++it) {
    float bv;
    int bi;
    if (v0 > v1 || (v0 == v1 && i0 < i1)) { bv = v0; bi = i0; }
    else { bv = v1; bi = i1; }
#pragma unroll
    for (int off = 32; off >= 1; off >>= 1) {
      float ov = __shfl_xor(bv, off);
      int oi = __shfl_xor(bi, off);
      if (ov > bv || (ov == bv && oi < bi)) { bv = ov; bi = oi; }
    }
    if (l == it) selk = bi;
    // remove winner (global key idx unique across candidates)
    if (i0 == bi) v0 = -1e30f;
    if (i1 == bi) v1 = -1e30f;
  }

  int rank = 0;
#pragma unroll
  for (int j = 0; j < NE; ++j) {
    int o = __shfl(selk, j);
    rank += (o < selk) ? 1 : 0;
  }
  if (l < NE) {
    int* o0 = out + (size_t)n * 2 * LSEQ * NE + (size_t)q * NE;
    int* o1p = o0 + (size_t)LSEQ * NE;
    o0[l] = q;
    o1p[rank] = selk;
  }
}

// ---------------------------------------------------------------------------
extern "C" void kernel_launch(void* const* d_in, const int* in_sizes, int n_in,
                              void* d_out, int out_size, void* d_ws, size_t ws_size,
                              hipStream_t stream) {
  const float* keys = (const float*)d_in[0];
  const float* query = (const float*)d_in[1];
  const float* Wk = (const float*)d_in[2];
  const float* Wq = (const float*)d_in[3];
  int* out = (int*)d_out;

  const size_t SPLIT = (size_t)NB * HH * LSEQ * DD;  // 4,194,304 elems
  __hip_bfloat16* qs1 = (__hip_bfloat16*)d_ws;
  __hip_bfloat16* qs2 = qs1 + SPLIT;
  __hip_bfloat16* qs3 = qs2 + SPLIT;
  __hip_bfloat16* ks1 = qs3 + SPLIT;
  __hip_bfloat16* ks2 = ks1 + SPLIT;
  __hip_bfloat16* ks3 = ks2 + SPLIT;
  float* invp = (float*)(ks3 + SPLIT);                     // 512 KB
  float* candV = invp + (size_t)NB * HH * LSEQ;            // 8.4 MB
  int* candI = (int*)(candV + (size_t)NB * LSEQ * 4 * NE); // 8.4 MB

  proj_kernel<<<NB * LSEQ, 256, 0, stream>>>(query, Wq, 0.0625f * 1.44269504088896340736f,
                                             qs1, qs2, qs3);
  proj_kernel<<<NB * LSEQ, 256, 0, stream>>>(keys, Wk, 1.0f, ks1, ks2, ks3);
  zinv_kernel<<<NB * (LSEQ / ZQT), ZNT, 0, stream>>>(qs1, qs2, qs3, ks1, ks2, ks3, invp);
  mean_topk_kernel<<<NB * (LSEQ / MQT) * 4, MNT, 0, stream>>>(qs1, qs2, qs3, ks1, ks2, ks3,
                                                              invp, candV, candI);
  merge_kernel<<<NB * LSEQ / 8, 512, 0, stream>>>(candV, candI, out);
}

// Round 10
// 672.677 us; speedup vs baseline: 1.8761x; 1.8761x over previous
//
#include <hip/hip_runtime.h>
#include <hip/hip_bf16.h>

#define NB 8
#define LSEQ 2048
#define HH 8
#define DD 32
#define EE 256
#define NE 32
#define QT 16      // queries per block (one MFMA tile of rows)
#define NTH 1024
#define KHALF 1024 // keys per block (half the row)
#define KW 64      // keys per wave (16 waves x 64 = 1024)
#define NTILE 4    // KW / 16
#define SMS 1026   // smean row stride (words); 1026%32==2 -> 2-way RMW (free)

// zinv geometry (round-8 proven)
#define ZQT 64
#define ZNT 512
#define ZKW 256
#define ZNTILE 16

typedef __attribute__((ext_vector_type(8))) short short8;
typedef __attribute__((ext_vector_type(4))) float f32x4;

// ---------------------------------------------------------------------------
// K1: per-head projection -> 3-way bf16 split (hi/mid/lo ~ 24 mantissa bits).
// Q pass folds softmax temperature AND 1/ln2: scale = 1/(16*ln2) -> exp2.
// ---------------------------------------------------------------------------
__global__ __launch_bounds__(256) void proj_kernel(const float* __restrict__ x,
                                                   const float* __restrict__ W,
                                                   float scale,
                                                   __hip_bfloat16* __restrict__ o1,
                                                   __hip_bfloat16* __restrict__ o2,
                                                   __hip_bfloat16* __restrict__ o3) {
  const int b = blockIdx.x;  // n*L + l
  __shared__ float xs[EE];
  __shared__ float Ws[DD][DD + 1];
  const int t = threadIdx.x;
  xs[t] = x[(size_t)b * EE + t];
  for (int i = t; i < DD * DD; i += 256) Ws[i / DD][i % DD] = W[i];
  __syncthreads();
  const int h = t / DD, e = t % DD;
  float acc = 0.f;
#pragma unroll
  for (int d = 0; d < DD; ++d) acc = fmaf(xs[h * DD + d], Ws[e][d], acc);
  acc *= scale;
  const int n = b / LSEQ, l = b % LSEQ;
  const size_t oi = (((size_t)n * HH + h) * LSEQ + l) * DD + e;
  __hip_bfloat16 p1 = __float2bfloat16(acc);
  float r1 = acc - __bfloat162float(p1);
  __hip_bfloat16 p2 = __float2bfloat16(r1);
  float r2 = r1 - __bfloat162float(p2);
  __hip_bfloat16 p3 = __float2bfloat16(r2);
  o1[oi] = p1;
  o2[oi] = p2;
  o3[oi] = p3;
}

// ---------------------------------------------------------------------------
// K2: Z -> inv = rcp(Z) (round-8 proven, unchanged).
// inv is a per-(h,row) uniform scale: order-safe in any summation order.
// ---------------------------------------------------------------------------
__global__ __launch_bounds__(ZNT) void zinv_kernel(
    const __hip_bfloat16* __restrict__ q1, const __hip_bfloat16* __restrict__ q2,
    const __hip_bfloat16* __restrict__ q3, const __hip_bfloat16* __restrict__ k1,
    const __hip_bfloat16* __restrict__ k2, const __hip_bfloat16* __restrict__ k3,
    float* __restrict__ invp) {
  __shared__ float zlds[HH][ZQT];

  const int t = threadIdx.x;
  const int w = t >> 6, l = t & 63;
  const int g = l >> 4, c = l & 15;
  const int n = blockIdx.x & 7;
  const int q0 = (blockIdx.x >> 3) * ZQT;

  ((float*)zlds)[t] = 0.f;
  __syncthreads();

  for (int h = 0; h < HH; ++h) {
    const size_t hb = ((size_t)n * HH + h) * LSEQ;
    short8 aH[4], aM[4], aL[4];
#pragma unroll
    for (int qs = 0; qs < 4; ++qs) {
      const size_t qoff = (hb + q0 + qs * 16 + c) * DD + (size_t)g * 8;
      aH[qs] = *(const short8*)(q1 + qoff);
      aM[qs] = *(const short8*)(q2 + qoff);
      aL[qs] = *(const short8*)(q3 + qoff);
    }
    float Zl[4][4];
#pragma unroll
    for (int qs = 0; qs < 4; ++qs)
#pragma unroll
      for (int r = 0; r < 4; ++r) Zl[qs][r] = 0.f;

    for (int t2 = 0; t2 < ZNTILE; ++t2) {
      const size_t koff = (hb + (size_t)w * ZKW + t2 * 16 + c) * DD + (size_t)g * 8;
      const short8 bH = *(const short8*)(k1 + koff);
      const short8 bM = *(const short8*)(k2 + koff);
      const short8 bL = *(const short8*)(k3 + koff);
#pragma unroll
      for (int qs = 0; qs < 4; ++qs) {
        f32x4 a = {0.f, 0.f, 0.f, 0.f};
        a = __builtin_amdgcn_mfma_f32_16x16x32_bf16(aH[qs], bH, a, 0, 0, 0);
        a = __builtin_amdgcn_mfma_f32_16x16x32_bf16(aH[qs], bM, a, 0, 0, 0);
        a = __builtin_amdgcn_mfma_f32_16x16x32_bf16(aM[qs], bH, a, 0, 0, 0);
        a = __builtin_amdgcn_mfma_f32_16x16x32_bf16(aH[qs], bL, a, 0, 0, 0);
        a = __builtin_amdgcn_mfma_f32_16x16x32_bf16(aL[qs], bH, a, 0, 0, 0);
        a = __builtin_amdgcn_mfma_f32_16x16x32_bf16(aM[qs], bM, a, 0, 0, 0);
#pragma unroll
        for (int r = 0; r < 4; ++r) Zl[qs][r] += exp2f(a[r]);
      }
    }
#pragma unroll
    for (int msk = 1; msk <= 8; msk <<= 1)
#pragma unroll
      for (int qs = 0; qs < 4; ++qs)
#pragma unroll
        for (int r = 0; r < 4; ++r) Zl[qs][r] += __shfl_xor(Zl[qs][r], msk);
    if (c == 0) {
#pragma unroll
      for (int qs = 0; qs < 4; ++qs)
#pragma unroll
        for (int r = 0; r < 4; ++r) atomicAdd(&zlds[h][qs * 16 + g * 4 + r], Zl[qs][r]);
    }
  }
  __syncthreads();
  const int h2 = t >> 6, qi = t & 63;
  invp[((size_t)n * HH + h2) * LSEQ + q0 + qi] = __builtin_amdgcn_rcpf(zlds[h2][qi]);
}

// ---------------------------------------------------------------------------
// K3: half-K mean + per-half top-32 candidates.
// Block = (n, 16-query tile, half of 1024 keys). 16 waves; wave w owns keys
// [k0 + w*64, k0 + (w+1)*64). Head loop is BARRIER-FREE (R8-proven): loads ->
// 6 MFMA -> exp2 -> x inv -> LDS RMW (thread-private slots, 2-way banks).
// smean = 16 x 1026 words = 66 KB -> 2 blocks/CU -> 32 waves/CU (vs R8's 16):
// doubles latency hiding, which the R8 analysis says is the binding constraint.
// C fragment mapping (verified rounds 2-9): row(query)=g*4+r, col(key)=c.
// ---------------------------------------------------------------------------
__global__ __launch_bounds__(NTH) void mean_topk_kernel(
    const __hip_bfloat16* __restrict__ q1, const __hip_bfloat16* __restrict__ q2,
    const __hip_bfloat16* __restrict__ q3, const __hip_bfloat16* __restrict__ k1,
    const __hip_bfloat16* __restrict__ k2, const __hip_bfloat16* __restrict__ k3,
    const float* __restrict__ invp, float* __restrict__ candV,
    int* __restrict__ candI) {
  __shared__ float smean[QT * SMS];  // 65.7 KB
  __shared__ float ilds[HH][QT];     // 512 B

  const int t = threadIdx.x;
  const int w = t >> 6, l = t & 63;
  const int g = l >> 4, c = l & 15;
  const int n = blockIdx.x & 7;       // 2048 blocks, %8==0: bijective XCD map
  const int rest = blockIdx.x >> 3;   // 0..255
  const int qt = rest & 127;
  const int half = rest >> 7;         // 0..1
  const int q0 = qt * QT;
  const int k0 = half * KHALF;

  for (int i = t; i < QT * SMS; i += NTH) smean[i] = 0.f;
  if (t < HH * QT) {
    const int h = t >> 4, qi = t & 15;
    ilds[h][qi] = invp[((size_t)n * HH + h) * LSEQ + q0 + qi];
  }
  float* macc = &smean[(g * 4) * SMS + w * KW + c];
  __syncthreads();

  for (int h = 0; h < HH; ++h) {
    const size_t hb = ((size_t)n * HH + h) * LSEQ;
    const size_t qoff = (hb + q0 + c) * DD + (size_t)g * 8;
    const short8 aH = *(const short8*)(q1 + qoff);
    const short8 aM = *(const short8*)(q2 + qoff);
    const short8 aL = *(const short8*)(q3 + qoff);
    float iv[4];
#pragma unroll
    for (int r = 0; r < 4; ++r) iv[r] = ilds[h][g * 4 + r];

#pragma unroll
    for (int t2 = 0; t2 < NTILE; ++t2) {
      const size_t koff = (hb + k0 + (size_t)w * KW + t2 * 16 + c) * DD + (size_t)g * 8;
      const short8 bH = *(const short8*)(k1 + koff);
      const short8 bM = *(const short8*)(k2 + koff);
      const short8 bL = *(const short8*)(k3 + koff);
      f32x4 a = {0.f, 0.f, 0.f, 0.f};
      a = __builtin_amdgcn_mfma_f32_16x16x32_bf16(aH, bH, a, 0, 0, 0);
      a = __builtin_amdgcn_mfma_f32_16x16x32_bf16(aH, bM, a, 0, 0, 0);
      a = __builtin_amdgcn_mfma_f32_16x16x32_bf16(aM, bH, a, 0, 0, 0);
      a = __builtin_amdgcn_mfma_f32_16x16x32_bf16(aH, bL, a, 0, 0, 0);
      a = __builtin_amdgcn_mfma_f32_16x16x32_bf16(aL, bH, a, 0, 0, 0);
      a = __builtin_amdgcn_mfma_f32_16x16x32_bf16(aM, bM, a, 0, 0, 0);
#pragma unroll
      for (int r = 0; r < 4; ++r) {
        float* p = macc + r * SMS + t2 * 16;
        *p = fmaf(exp2f(a[r]), iv[r], *p);
      }
    }
  }
  __syncthreads();

  // --- top-32 of this 1024 slice: wave w owns row w; local k = j*64 + l ---
  float* row = &smean[w * SMS];
  float vals[16];
  float v1 = -1e30f, v2 = -1e30f;
  int i1 = 1 << 30, i2 = 1 << 30;
#pragma unroll
  for (int j = 0; j < 16; ++j) {
    float v = row[j * 64 + l];
    vals[j] = v;
    const int k = j * 64 + l;
    if (v > v1) { v2 = v1; i2 = i1; v1 = v; i1 = k; }
    else if (v > v2) { v2 = v; i2 = k; }
  }
  unsigned rem = 0u;
  int selk = 0;
  float selv = 0.f;
#pragma unroll 1
  for (int it = 0; it < NE; ++it) {
    float bv = v1;
    int bk = i1;
#pragma unroll
    for (int off = 32; off >= 1; off >>= 1) {
      float ov = __shfl_xor(bv, off);
      int ok = __shfl_xor(bk, off);
      if (ov > bv || (ov == bv && ok < bk)) { bv = ov; bk = ok; }
    }
    if (l == it) { selk = bk; selv = bv; }
    if (i1 == bk) {  // this lane supplied the winner (k%64==l: unique owner)
      rem |= 1u << (bk >> 6);
      if (i2 != (1 << 30)) {  // promote cached second
        v1 = v2; i1 = i2;
        v2 = -1e30f; i2 = 1 << 30;
      } else {  // rare: rebuild top-2 from masked registers
        v1 = -1e30f; i1 = 1 << 30;
        v2 = -1e30f; i2 = 1 << 30;
#pragma unroll
        for (int j = 0; j < 16; ++j) {
          float v = ((rem >> j) & 1u) ? -1e30f : vals[j];
          const int k = j * 64 + l;
          if (v > v1) { v2 = v1; i2 = i1; v1 = v; i1 = k; }
          else if (v > v2) { v2 = v; i2 = k; }
        }
      }
    }
  }
  if (l < NE) {
    const size_t cb = (((size_t)n * LSEQ + q0 + w) * 2 + half) * NE;
    candV[cb + l] = selv;
    candI[cb + l] = k0 + selk;  // global key index
  }
}

// ---------------------------------------------------------------------------
// K4: merge 2x32 half candidates per row (1 per lane) -> final top-32 ->
// sorted edges. Same (val desc, idx asc) tie semantics; key indices unique.
// ---------------------------------------------------------------------------
__global__ __launch_bounds__(512) void merge_kernel(const float* __restrict__ candV,
                                                    const int* __restrict__ candI,
                                                    int* __restrict__ out) {
  const int t = threadIdx.x;
  const int w = t >> 6, l = t & 63;
  const size_t rowg = (size_t)blockIdx.x * 8 + w;  // n*2048 + q
  const int n = (int)(rowg >> 11), q = (int)(rowg & 2047);

  float v0 = candV[rowg * 64 + l];
  int i0 = candI[rowg * 64 + l];

  int selk = 0;
#pragma unroll 1
  for (int it = 0; it < NE; ++it) {
    float bv = v0;
    int bi = i0;
#pragma unroll
    for (int off = 32; off >= 1; off >>= 1) {
      float ov = __shfl_xor(bv, off);
      int oi = __shfl_xor(bi, off);
      if (ov > bv || (ov == bv && oi < bi)) { bv = ov; bi = oi; }
    }
    if (l == it) selk = bi;
    if (i0 == bi) v0 = -1e30f;  // remove winner (unique key idx)
  }

  int rank = 0;
#pragma unroll
  for (int j = 0; j < NE; ++j) {
    int o = __shfl(selk, j);
    rank += (o < selk) ? 1 : 0;
  }
  if (l < NE) {
    int* o0 = out + (size_t)n * 2 * LSEQ * NE + (size_t)q * NE;
    int* o1p = o0 + (size_t)LSEQ * NE;
    o0[l] = q;
    o1p[rank] = selk;
  }
}

// ---------------------------------------------------------------------------
extern "C" void kernel_launch(void* const* d_in, const int* in_sizes, int n_in,
                              void* d_out, int out_size, void* d_ws, size_t ws_size,
                              hipStream_t stream) {
  const float* keys = (const float*)d_in[0];
  const float* query = (const float*)d_in[1];
  const float* Wk = (const float*)d_in[2];
  const float* Wq = (const float*)d_in[3];
  int* out = (int*)d_out;

  const size_t SPLIT = (size_t)NB * HH * LSEQ * DD;  // 4,194,304 elems
  __hip_bfloat16* qs1 = (__hip_bfloat16*)d_ws;
  __hip_bfloat16* qs2 = qs1 + SPLIT;
  __hip_bfloat16* qs3 = qs2 + SPLIT;
  __hip_bfloat16* ks1 = qs3 + SPLIT;
  __hip_bfloat16* ks2 = ks1 + SPLIT;
  __hip_bfloat16* ks3 = ks2 + SPLIT;
  float* invp = (float*)(ks3 + SPLIT);                     // 512 KB
  float* candV = invp + (size_t)NB * HH * LSEQ;            // 4.2 MB
  int* candI = (int*)(candV + (size_t)NB * LSEQ * 2 * NE); // 4.2 MB

  proj_kernel<<<NB * LSEQ, 256, 0, stream>>>(query, Wq, 0.0625f * 1.44269504088896340736f,
                                             qs1, qs2, qs3);
  proj_kernel<<<NB * LSEQ, 256, 0, stream>>>(keys, Wk, 1.0f, ks1, ks2, ks3);
  zinv_kernel<<<NB * (LSEQ / ZQT), ZNT, 0, stream>>>(qs1, qs2, qs3, ks1, ks2, ks3, invp);
  mean_topk_kernel<<<NB * (LSEQ / QT) * 2, NTH, 0, stream>>>(qs1, qs2, qs3, ks1, ks2, ks3,
                                                             invp, candV, candI);
  merge_kernel<<<NB * LSEQ / 8, 512, 0, stream>>>(candV, candI, out);
}